// Round 14
// baseline (214.717 us; speedup 1.0000x reference)
//
#include <hip/hip_runtime.h>
#include <math.h>

using short8 = __attribute__((ext_vector_type(8))) short;
using f32x4 = __attribute__((ext_vector_type(4))) float;

#define CAP 48   // edge-bucket capacity; P(Poisson(6) >= 48) ~ 1e-30

__device__ inline short f2bf(float f) {
    unsigned u = __builtin_bit_cast(unsigned, f);
    unsigned r = (u + 0x7fffu + ((u >> 16) & 1u)) >> 16;
    return (short)r;
}
__device__ inline float bf2f(short s) {
    unsigned u = ((unsigned)(unsigned short)s) << 16;
    return __builtin_bit_cast(float, u);
}

// async global->LDS, 16B per lane. Dest is wave-uniform base + lane*16 (HW);
// source address is per-lane (pre-swizzled for bank-conflict-free reads).
typedef const void __attribute__((address_space(1))) gvoid_t;
typedef void __attribute__((address_space(3))) svoid_t;
__device__ inline void gload16(const short* g, short* l) {
    __builtin_amdgcn_global_load_lds((gvoid_t*)g, (svoid_t*)l, 16, 0, 0);
}

// ---------------- fused prep: x->bf16, W transposes, edge bucketing ----------------
// deg[] must be zeroed (memsetAsync) before this kernel. (eslot NOT zeroed;
// gather guards padding indices.)

__global__ void prep_kernel(const float* __restrict__ x, const float* __restrict__ W1,
                            const float* __restrict__ W2, const float* __restrict__ Wc,
                            const int* __restrict__ src, const int* __restrict__ dst,
                            short* __restrict__ xb, short* __restrict__ Wt1,
                            short* __restrict__ Wt2, short* __restrict__ Wtc,
                            int* __restrict__ deg, int* __restrict__ eslot,
                            int n, int e) {
    int idx = blockIdx.x * blockDim.x + threadIdx.x;
    const int nx8 = n * 16;                      // N*128/8 groups of 8
    if (idx < nx8) {
        const float4* p = (const float4*)x + (size_t)idx * 2;
        float4 v0 = p[0], v1 = p[1];
        short8 o;
        o[0] = f2bf(v0.x); o[1] = f2bf(v0.y); o[2] = f2bf(v0.z); o[3] = f2bf(v0.w);
        o[4] = f2bf(v1.x); o[5] = f2bf(v1.y); o[6] = f2bf(v1.z); o[7] = f2bf(v1.w);
        ((short8*)xb)[idx] = o;
        return;
    }
    idx -= nx8;
    if (idx < 128 * 256) {                       // W1: K=128, N=256
        int k = idx >> 8, c = idx & 255;
        Wt1[c * 128 + k] = f2bf(W1[idx]);
        return;
    }
    idx -= 128 * 256;
    if (idx < 256 * 256) {                       // W2: K=256, N=256
        int k = idx >> 8, c = idx & 255;
        Wt2[c * 256 + k] = f2bf(W2[idx]);
        return;
    }
    idx -= 256 * 256;
    if (idx < 256 * 32) {                        // Wc: K=256, N=32
        int k = idx >> 5, c = idx & 31;
        Wtc[c * 256 + k] = f2bf(Wc[idx]);
        return;
    }
    idx -= 256 * 32;
    if (idx < e) {                               // edge bucketing
        int d = dst[idx], s = src[idx];
        int pos = atomicAdd(&deg[d], 1);
        if (pos < CAP) eslot[(size_t)d * CAP + pos] = s;
    }
}

// ---------------- bf16 MFMA GEMM 128x128, global_load_lds staging (layer 1) ----------------
// 4 waves; wave computes 64x64 via 4x4 of 16x16x32 MFMAs. Staging via
// global_load_lds width=16 into LINEAR [128][32] LDS; 16B chunk c of row r
// stored at chunk c ^ ((r>>1)&3) via pre-swizzled GLOBAL source; fragment
// reads apply the same XOR (bank-floor rate).

template<bool RELU_BF16OUT>
__global__ __launch_bounds__(256) void mfma_gemm128_kernel(
    const short* __restrict__ A, const short* __restrict__ Wt,
    const float* __restrict__ bias, void* __restrict__ Cout,
    int M, int K, int NC)
{
    __shared__ short As[128 * 32];
    __shared__ short Bs[128 * 32];

    const int tid = threadIdx.x;
    const int wave = tid >> 6, lane = tid & 63;
    const int m0 = blockIdx.y * 128, n0 = blockIdx.x * 128;
    const int wm = (wave >> 1) * 64, wn = (wave & 1) * 64;

    const int lr0 = tid >> 2;                 // rows 0..63   (issue 0)
    const int lr1 = 64 + lr0;                 // rows 64..127 (issue 1)
    const int cdst = tid & 3;
    const int cg0 = cdst ^ ((lr0 >> 1) & 3);
    const int cg1 = cdst ^ ((lr1 >> 1) & 3);
    int ga0 = m0 + lr0; if (ga0 >= M) ga0 = M - 1;
    int ga1 = m0 + lr1; if (ga1 >= M) ga1 = M - 1;
    int gb0 = n0 + lr0; if (gb0 >= NC) gb0 = NC - 1;
    int gb1 = n0 + lr1; if (gb1 >= NC) gb1 = NC - 1;
    const short* pa0 = A + (size_t)ga0 * K + cg0 * 8;
    const short* pa1 = A + (size_t)ga1 * K + cg1 * 8;
    const short* pb0 = Wt + (size_t)gb0 * K + cg0 * 8;
    const short* pb1 = Wt + (size_t)gb1 * K + cg1 * 8;

    short* lA0 = &As[(wave * 16) * 32];
    short* lA1 = &As[(64 + wave * 16) * 32];
    short* lB0 = &Bs[(wave * 16) * 32];
    short* lB1 = &Bs[(64 + wave * 16) * 32];

    f32x4 acc[4][4] = {};
    const int fr = lane & 15;
    const int cfrag = lane >> 4;
    const int swzr = (fr >> 1) & 3;

    for (int k0 = 0; k0 < K; k0 += 32) {
        gload16(pa0 + k0, lA0);
        gload16(pa1 + k0, lA1);
        gload16(pb0 + k0, lB0);
        gload16(pb1 + k0, lB1);
        __syncthreads();

        short8 af[4], bfv[4];
        #pragma unroll
        for (int mt = 0; mt < 4; ++mt) {
            int rr = wm + mt * 16 + fr;
            af[mt] = *(const short8*)&As[rr * 32 + ((cfrag ^ swzr) << 3)];
        }
        #pragma unroll
        for (int nt = 0; nt < 4; ++nt) {
            int rr = wn + nt * 16 + fr;
            bfv[nt] = *(const short8*)&Bs[rr * 32 + ((cfrag ^ swzr) << 3)];
        }

        #pragma unroll
        for (int mt = 0; mt < 4; ++mt)
            #pragma unroll
            for (int nt = 0; nt < 4; ++nt)
                acc[mt][nt] = __builtin_amdgcn_mfma_f32_16x16x32_bf16(
                    af[mt], bfv[nt], acc[mt][nt], 0, 0, 0);

        __syncthreads();
    }

    #pragma unroll
    for (int mt = 0; mt < 4; ++mt) {
        #pragma unroll
        for (int nt = 0; nt < 4; ++nt) {
            #pragma unroll
            for (int r = 0; r < 4; ++r) {
                int grow = m0 + wm + mt * 16 + (lane >> 4) * 4 + r;
                int gcol = n0 + wn + nt * 16 + (lane & 15);
                if (grow < M && gcol < NC) {
                    float v = acc[mt][nt][r] + bias[gcol];
                    if (RELU_BF16OUT)
                        ((short*)Cout)[(size_t)grow * NC + gcol] = f2bf(fmaxf(v, 0.f));
                    else
                        ((float*)Cout)[(size_t)grow * NC + gcol] = v;
                }
            }
        }
    }
}

// ---------------- fused layer 2: gather + GEMM + classifier (v5: 512 thr @ 32 KB) ----------------
// Constraint solve across R9/R10/R12/R13: allocatable LDS budget B in [80,96) KB
// (80->1 blk, 67.6->1, 64->1, 32->2, not 3). v5 is the discriminating test:
// 512 threads (8 waves), hT[64][256] = 32 KB -> predicted 2 blocks/CU = 16
// waves/CU (2x all prior rounds' TLP). Register math (~128/thread incl acc)
// allows exactly 4 waves/SIMD. Tile stays 64 rows (grid 782); gather has 16
// concurrent nodes/block and 4 quad-iterations/thread (half of R13).
// Phase-2 wave tile 32x64 (wm=(wave>>2)*32, wn=(wave&3)*64, acc[2][4]).
// Phase 4: waves 0-3 only. Same math and k-order -> bitwise-identical output.

__global__ __launch_bounds__(512, 4) void layer2_fused_kernel(
    const short* __restrict__ hA,     // [M,256] bf16 (layer-1 output)
    const int* __restrict__ deg, const int* __restrict__ eslot,
    const short* __restrict__ Wt2,    // [256 cols][256 k] bf16
    const float* __restrict__ b2,
    const short* __restrict__ Wtc,    // [32 cols][256 k] bf16
    const float* __restrict__ bc,
    float* __restrict__ out,          // [M,32] fp32
    int M)
{
    const int K = 256;
    __shared__ short hT[64 * 256];           // 32.0 KB

    const int tid = threadIdx.x;
    const int wave = tid >> 6, lane = tid & 63;
    const int m0 = blockIdx.x * 64;

    // ---- Phase 1: gather 64 rows of hB into hT (exact R0 math) ----
    {
        const int grp = tid >> 5;            // 0..15: node group
        const int gl  = tid & 31;            // feature chunk 0..31
        const int f   = gl * 8;
        for (int r0 = 0; r0 < 64; r0 += 16) {    // 4 iterations
            int r = r0 + grp;
            int node = m0 + r; if (node >= M) node = M - 1;
            int dg = deg[node];
            if (dg > CAP) dg = CAP;
            float di = rsqrtf((float)dg + 1.0f);
            float w = di * di;
            short8 hv = *(const short8*)(hA + (size_t)node * 256 + f);
            float a[8];
            #pragma unroll
            for (int j = 0; j < 8; ++j) a[j] = bf2f(hv[j]) * w;

            const int* bucket = eslot + (size_t)node * CAP;
            for (int e = 0; e < dg; e += 4) {
                int4 s4 = *(const int4*)(bucket + e);
                int i0 = s4.x;
                int i1 = (e + 1 < dg) ? s4.y : 0;
                int i2 = (e + 2 < dg) ? s4.z : 0;
                int i3 = (e + 3 < dg) ? s4.w : 0;
                int d0 = deg[i0], d1 = deg[i1], d2 = deg[i2], d3 = deg[i3];
                short8 v0 = *(const short8*)(hA + (size_t)i0 * 256 + f);
                short8 v1 = *(const short8*)(hA + (size_t)i1 * 256 + f);
                short8 v2 = *(const short8*)(hA + (size_t)i2 * 256 + f);
                short8 v3 = *(const short8*)(hA + (size_t)i3 * 256 + f);
                float w0 = rsqrtf((float)d0 + 1.0f) * di;
                float w1 = (e + 1 < dg) ? rsqrtf((float)d1 + 1.0f) * di : 0.f;
                float w2 = (e + 2 < dg) ? rsqrtf((float)d2 + 1.0f) * di : 0.f;
                float w3 = (e + 3 < dg) ? rsqrtf((float)d3 + 1.0f) * di : 0.f;
                #pragma unroll
                for (int j = 0; j < 8; ++j) {
                    a[j] = fmaf(bf2f(v0[j]), w0, a[j]);
                    a[j] = fmaf(bf2f(v1[j]), w1, a[j]);
                    a[j] = fmaf(bf2f(v2[j]), w2, a[j]);
                    a[j] = fmaf(bf2f(v3[j]), w3, a[j]);
                }
            }
            short8 o;
            #pragma unroll
            for (int j = 0; j < 8; ++j) o[j] = f2bf(a[j]);
            *(short8*)&hT[r * 256 + ((gl ^ (r & 7)) << 3)] = o;   // swizzled chunk
        }
    }
    __syncthreads();   // hT resident for all waves

    // ---- Phase 2: T = relu(hT @ W2 + b2); wave tile 32x64
    //      (wm=(wave>>2)*32, wn=(wave&3)*64); B direct from global (L2-hot);
    //      no per-K-step barriers ----
    const int wm = (wave >> 2) * 32;         // 0,32
    const int wn = (wave & 3) * 64;          // 0,64,128,192
    const int fr = lane & 15;
    const int cfrag = lane >> 4;
    const int fk = cfrag * 8;                // k-chunk base (shorts)
    const int rk = fr & 7;                   // swizzle key (wave rows are +multiples of 16)

    f32x4 acc[2][4] = {};
    for (int k0 = 0; k0 < K; k0 += 32) {
        const int cswz = (((k0 >> 3) + cfrag) ^ rk) << 3;   // swizzled chunk offset
        short8 af[2], bfv[4];
        #pragma unroll
        for (int mt = 0; mt < 2; ++mt)
            af[mt] = *(const short8*)&hT[(wm + mt * 16 + fr) * 256 + cswz];
        #pragma unroll
        for (int nt = 0; nt < 4; ++nt)
            bfv[nt] = *(const short8*)(Wt2 + (size_t)(wn + nt * 16 + fr) * K + k0 + fk);

        #pragma unroll
        for (int mt = 0; mt < 2; ++mt)
            #pragma unroll
            for (int nt = 0; nt < 4; ++nt)
                acc[mt][nt] = __builtin_amdgcn_mfma_f32_16x16x32_bf16(
                    af[mt], bfv[nt], acc[mt][nt], 0, 0, 0);
    }
    __syncthreads();   // all phase-2 hT reads complete -> safe to overwrite

    // ---- Phase 3: bias+relu -> bf16 T tile (overwrites hT, same swizzle) ----
    #pragma unroll
    for (int mt = 0; mt < 2; ++mt) {
        #pragma unroll
        for (int nt = 0; nt < 4; ++nt) {
            #pragma unroll
            for (int r = 0; r < 4; ++r) {
                int lrow = wm + mt * 16 + (lane >> 4) * 4 + r;
                int gcol = wn + nt * 16 + fr;
                float v = acc[mt][nt][r] + b2[gcol];
                int cs = (gcol >> 3) ^ (lrow & 7);
                hT[lrow * 256 + cs * 8 + (gcol & 7)] = f2bf(fmaxf(v, 0.f));
            }
        }
    }
    __syncthreads();

    // ---- Phase 4: out = T @ Wc + bc (gemmc's exact k-order / C mapping);
    //      waves 0..3 handle rows wave*16..wave*16+15 (4x16 = 64 rows) ----
    if (wave < 4) {
        f32x4 c2[2] = {};
        for (int k0 = 0; k0 < K; k0 += 32) {
            const int cswz = (((k0 >> 3) + cfrag) ^ rk) << 3;   // row&7 == fr&7 here too
            short8 a8 = *(const short8*)&hT[(wave * 16 + fr) * 256 + cswz];
            #pragma unroll
            for (int nt = 0; nt < 2; ++nt) {
                short8 b8 = *(const short8*)(Wtc + (size_t)(nt * 16 + fr) * K + k0 + fk);
                c2[nt] = __builtin_amdgcn_mfma_f32_16x16x32_bf16(a8, b8, c2[nt], 0, 0, 0);
            }
        }
        #pragma unroll
        for (int nt = 0; nt < 2; ++nt) {
            #pragma unroll
            for (int r = 0; r < 4; ++r) {
                int grow = m0 + wave * 16 + (lane >> 4) * 4 + r;
                int gcol = nt * 16 + fr;
                if (grow < M)
                    out[(size_t)grow * 32 + gcol] = c2[nt][r] + bc[gcol];
            }
        }
    }
}

// ---------------- bucket gather, padded 4-wide rounds (exact R0; layer 1) ----------------

template<int LPN>
__global__ __launch_bounds__(256) void gather_kernel(
    const short* __restrict__ h, const int* __restrict__ deg,
    const int* __restrict__ eslot, short* __restrict__ out, int n)
{
    const int F = LPN * 8;
    int node = (blockIdx.x * 256 + threadIdx.x) / LPN;
    if (node >= n) return;
    int lane = threadIdx.x % LPN;
    int f = lane * 8;

    int dg = deg[node];
    if (dg > CAP) dg = CAP;
    float di = rsqrtf((float)dg + 1.0f);
    float w = di * di;

    const size_t rb = (size_t)node * F + f;
    short8 hv = *(const short8*)(h + rb);
    float a[8];
    #pragma unroll
    for (int j = 0; j < 8; ++j) a[j] = bf2f(hv[j]) * w;

    const int* bucket = eslot + (size_t)node * CAP;
    for (int e = 0; e < dg; e += 4) {
        int4 s4 = *(const int4*)(bucket + e);
        // guard padding lanes BEFORE any dereference (slots past dg are poison)
        int i0 = s4.x;
        int i1 = (e + 1 < dg) ? s4.y : 0;
        int i2 = (e + 2 < dg) ? s4.z : 0;
        int i3 = (e + 3 < dg) ? s4.w : 0;
        int d0 = deg[i0], d1 = deg[i1], d2 = deg[i2], d3 = deg[i3];
        short8 v0 = *(const short8*)(h + (size_t)i0 * F + f);
        short8 v1 = *(const short8*)(h + (size_t)i1 * F + f);
        short8 v2 = *(const short8*)(h + (size_t)i2 * F + f);
        short8 v3 = *(const short8*)(h + (size_t)i3 * F + f);
        float w0 = rsqrtf((float)d0 + 1.0f) * di;
        float w1 = (e + 1 < dg) ? rsqrtf((float)d1 + 1.0f) * di : 0.f;
        float w2 = (e + 2 < dg) ? rsqrtf((float)d2 + 1.0f) * di : 0.f;
        float w3 = (e + 3 < dg) ? rsqrtf((float)d3 + 1.0f) * di : 0.f;
        #pragma unroll
        for (int j = 0; j < 8; ++j) {
            a[j] = fmaf(bf2f(v0[j]), w0, a[j]);
            a[j] = fmaf(bf2f(v1[j]), w1, a[j]);
            a[j] = fmaf(bf2f(v2[j]), w2, a[j]);
            a[j] = fmaf(bf2f(v3[j]), w3, a[j]);
        }
    }
    short8 o;
    #pragma unroll
    for (int j = 0; j < 8; ++j) o[j] = f2bf(a[j]);
    *(short8*)(out + rb) = o;
}

// ---------------- launch ----------------

extern "C" void kernel_launch(void* const* d_in, const int* in_sizes, int n_in,
                              void* d_out, int out_size, void* d_ws, size_t ws_size,
                              hipStream_t stream) {
    const float* x  = (const float*)d_in[0];
    const int*   ei = (const int*)d_in[1];
    const float* W1 = (const float*)d_in[2];
    const float* b1 = (const float*)d_in[3];
    const float* W2 = (const float*)d_in[4];
    const float* b2 = (const float*)d_in[5];
    const float* Wc = (const float*)d_in[6];
    const float* bc = (const float*)d_in[7];
    float* out = (float*)d_out;

    const int E = in_sizes[1] / 2;
    const int N = in_sizes[0] / 128;
    const int F_IN = 128, H = 256;
    const int* src = ei;
    const int* dst = ei + E;

    // workspace layout (shorts first, 16B aligned)
    short* xb   = (short*)d_ws;                     // N*128
    short* aggX = xb + (size_t)N * 128;             // N*128
    short* hA   = aggX + (size_t)N * 128;           // N*256
    short* Wt1  = hA + (size_t)N * 256;             // 256*128
    short* Wt2  = Wt1 + 256 * 128;                  // 256*256
    short* Wtc  = Wt2 + 256 * 256;                  // 32*256
    int*   deg  = (int*)(Wtc + 32 * 256);           // N
    int*   eslot= deg + N;                          // N*CAP (16B-aligned: N*CAP*4)

    const int TB = 256;

    hipMemsetAsync(deg, 0, (size_t)N * sizeof(int), stream);

    const int prep_total = N * 16 + 128 * 256 + 256 * 256 + 256 * 32 + E;
    prep_kernel<<<(prep_total + TB - 1) / TB, TB, 0, stream>>>(
        x, W1, W2, Wc, src, dst, xb, Wt1, Wt2, Wtc, deg, eslot, N, E);

    const int gy = (N + 127) / 128;
    const int gy64 = (N + 63) / 64;

    // layer 1: aggX = A_hat @ X ; hA = relu(aggX @ W1 + b1)
    gather_kernel<16><<<((size_t)N * 16 + TB - 1) / TB, TB, 0, stream>>>(
        xb, deg, eslot, aggX, N);
    mfma_gemm128_kernel<true><<<dim3(H / 128, gy), 256, 0, stream>>>(aggX, Wt1, b1, hA, N, F_IN, H);

    // layer 2 + classifier, fully fused (gather -> LDS -> GEMM -> classifier):
    //   out = relu((A_hat @ hA) @ W2 + b2) @ Wc + bc
    layer2_fused_kernel<<<gy64, 512, 0, stream>>>(
        hA, deg, eslot, Wt2, b2, Wtc, bc, out, N);
}

// Round 15
// 182.223 us; speedup vs baseline: 1.1783x; 1.1783x over previous
//
#include <hip/hip_runtime.h>
#include <math.h>

using short8 = __attribute__((ext_vector_type(8))) short;
using f32x4 = __attribute__((ext_vector_type(4))) float;

#define CAP 48   // edge-bucket capacity; P(Poisson(6) >= 48) ~ 1e-30

__device__ inline short f2bf(float f) {
    unsigned u = __builtin_bit_cast(unsigned, f);
    unsigned r = (u + 0x7fffu + ((u >> 16) & 1u)) >> 16;
    return (short)r;
}
__device__ inline float bf2f(short s) {
    unsigned u = ((unsigned)(unsigned short)s) << 16;
    return __builtin_bit_cast(float, u);
}

// async global->LDS, 16B per lane. Dest is wave-uniform base + lane*16 (HW);
// source address is per-lane (pre-swizzled for bank-conflict-free reads).
typedef const void __attribute__((address_space(1))) gvoid_t;
typedef void __attribute__((address_space(3))) svoid_t;
__device__ inline void gload16(const short* g, short* l) {
    __builtin_amdgcn_global_load_lds((gvoid_t*)g, (svoid_t*)l, 16, 0, 0);
}

// ---------------- fused prep: x->bf16, W transposes, edge bucketing ----------------
// deg[] must be zeroed (memsetAsync) before this kernel. (eslot NOT zeroed;
// gather guards padding indices.)

__global__ void prep_kernel(const float* __restrict__ x, const float* __restrict__ W1,
                            const float* __restrict__ W2, const float* __restrict__ Wc,
                            const int* __restrict__ src, const int* __restrict__ dst,
                            short* __restrict__ xb, short* __restrict__ Wt1,
                            short* __restrict__ Wt2, short* __restrict__ Wtc,
                            int* __restrict__ deg, int* __restrict__ eslot,
                            int n, int e) {
    int idx = blockIdx.x * blockDim.x + threadIdx.x;
    const int nx8 = n * 16;                      // N*128/8 groups of 8
    if (idx < nx8) {
        const float4* p = (const float4*)x + (size_t)idx * 2;
        float4 v0 = p[0], v1 = p[1];
        short8 o;
        o[0] = f2bf(v0.x); o[1] = f2bf(v0.y); o[2] = f2bf(v0.z); o[3] = f2bf(v0.w);
        o[4] = f2bf(v1.x); o[5] = f2bf(v1.y); o[6] = f2bf(v1.z); o[7] = f2bf(v1.w);
        ((short8*)xb)[idx] = o;
        return;
    }
    idx -= nx8;
    if (idx < 128 * 256) {                       // W1: K=128, N=256
        int k = idx >> 8, c = idx & 255;
        Wt1[c * 128 + k] = f2bf(W1[idx]);
        return;
    }
    idx -= 128 * 256;
    if (idx < 256 * 256) {                       // W2: K=256, N=256
        int k = idx >> 8, c = idx & 255;
        Wt2[c * 256 + k] = f2bf(W2[idx]);
        return;
    }
    idx -= 256 * 256;
    if (idx < 256 * 32) {                        // Wc: K=256, N=32
        int k = idx >> 5, c = idx & 31;
        Wtc[c * 256 + k] = f2bf(Wc[idx]);
        return;
    }
    idx -= 256 * 32;
    if (idx < e) {                               // edge bucketing
        int d = dst[idx], s = src[idx];
        int pos = atomicAdd(&deg[d], 1);
        if (pos < CAP) eslot[(size_t)d * CAP + pos] = s;
    }
}

// ---------------- fused layer 1: gather + GEMM (R9 template, K=128) ----------------
// 512 threads / 8 waves (2x4). Phase 1: gather 128 rows of aggX = A_hat @ X
// into hT[128][128] (32KB, chunk-XOR swizzled; exact R0 gather math).
// Phase 2: hA = relu(hT @ W1 + b1), B staged via gload16 (R9's exact
// pre-issue + 2-barrier-per-K-step loop; K=128 -> 4 steps), epilogue writes
// bf16 hA directly to global. Same MFMA operand values and k-order as the
// old gemm1 -> bitwise-identical output. Eliminates aggX write+read
// (25.6 MB) and one device drain. LDS = 32 + 16 = 48 KB.

__global__ __launch_bounds__(512, 4) void layer1_fused_kernel(
    const short* __restrict__ xb,     // [M,128] bf16
    const int* __restrict__ deg, const int* __restrict__ eslot,
    const short* __restrict__ Wt1,    // [256 cols][128 k] bf16
    const float* __restrict__ b1,
    short* __restrict__ hA,           // [M,256] bf16 out
    int M)
{
    const int K = 128;
    __shared__ short hT[128 * 128];          // 32 KB
    __shared__ short Bs[256 * 32];           // 16 KB (one K-step of Wt1)

    const int tid = threadIdx.x;
    const int wave = tid >> 6, lane = tid & 63;
    const int m0 = blockIdx.x * 128;

    // ---- B staging geometry (Wt1 rows 0..255, 32 shorts per K-step) ----
    const int srow = tid >> 2;               // 0..127
    const int cdst = tid & 3;
    const int lrB0 = srow, lrB1 = 128 + srow;
    const int cg0 = cdst ^ ((lrB0 >> 1) & 3);
    const int cg1 = cdst ^ ((lrB1 >> 1) & 3);
    const short* pb0 = Wt1 + (size_t)lrB0 * K + cg0 * 8;
    const short* pb1 = Wt1 + (size_t)lrB1 * K + cg1 * 8;
    short* lB0 = &Bs[(wave * 16) * 32];
    short* lB1 = &Bs[(128 + wave * 16) * 32];

    // pre-issue K-step 0 staging (no deps; lands during the gather phase)
    gload16(pb0, lB0);
    gload16(pb1, lB1);

    // ---- Phase 1: gather 128 rows of aggX into hT (exact R0 math, F=128) ----
    {
        const int grp = tid >> 4;            // 0..31: node group
        const int gl  = tid & 15;            // feature chunk 0..15
        const int f   = gl * 8;
        for (int r0 = 0; r0 < 128; r0 += 32) {   // 4 iterations
            int r = r0 + grp;
            int node = m0 + r; if (node >= M) node = M - 1;
            int dg = deg[node];
            if (dg > CAP) dg = CAP;
            float di = rsqrtf((float)dg + 1.0f);
            float w = di * di;
            short8 hv = *(const short8*)(xb + (size_t)node * 128 + f);
            float a[8];
            #pragma unroll
            for (int j = 0; j < 8; ++j) a[j] = bf2f(hv[j]) * w;

            const int* bucket = eslot + (size_t)node * CAP;
            for (int e = 0; e < dg; e += 4) {
                int4 s4 = *(const int4*)(bucket + e);
                int i0 = s4.x;
                int i1 = (e + 1 < dg) ? s4.y : 0;
                int i2 = (e + 2 < dg) ? s4.z : 0;
                int i3 = (e + 3 < dg) ? s4.w : 0;
                int d0 = deg[i0], d1 = deg[i1], d2 = deg[i2], d3 = deg[i3];
                short8 v0 = *(const short8*)(xb + (size_t)i0 * 128 + f);
                short8 v1 = *(const short8*)(xb + (size_t)i1 * 128 + f);
                short8 v2 = *(const short8*)(xb + (size_t)i2 * 128 + f);
                short8 v3 = *(const short8*)(xb + (size_t)i3 * 128 + f);
                float w0 = rsqrtf((float)d0 + 1.0f) * di;
                float w1 = (e + 1 < dg) ? rsqrtf((float)d1 + 1.0f) * di : 0.f;
                float w2 = (e + 2 < dg) ? rsqrtf((float)d2 + 1.0f) * di : 0.f;
                float w3 = (e + 3 < dg) ? rsqrtf((float)d3 + 1.0f) * di : 0.f;
                #pragma unroll
                for (int j = 0; j < 8; ++j) {
                    a[j] = fmaf(bf2f(v0[j]), w0, a[j]);
                    a[j] = fmaf(bf2f(v1[j]), w1, a[j]);
                    a[j] = fmaf(bf2f(v2[j]), w2, a[j]);
                    a[j] = fmaf(bf2f(v3[j]), w3, a[j]);
                }
            }
            short8 o;
            #pragma unroll
            for (int j = 0; j < 8; ++j) o[j] = f2bf(a[j]);
            *(short8*)&hT[r * 128 + ((gl ^ (r & 7)) << 3)] = o;   // swizzled chunk
        }
    }

    // ---- Phase 2: hA = relu(hT @ W1 + b1); R9's staged-B loop; K=128 ----
    const int wm = (wave >> 2) * 64;         // 0,64
    const int wn = (wave & 3) * 64;          // 0,64,128,192
    const int fr = lane & 15;
    const int cfrag = lane >> 4;
    const int rk = fr & 7;                   // hT swizzle key (wave rows +16k)
    const int swzr = (fr >> 1) & 3;          // Bs swizzle key (R9 pattern)

    f32x4 acc[4][4] = {};
    for (int k0 = 0; k0 < K; k0 += 32) {
        __syncthreads();   // Bs[k0] resident; hT writes visible (iter 0); prior reads done

        const int cswz = (((k0 >> 3) + cfrag) ^ rk) << 3;   // hT swizzled chunk offset
        short8 af[4], bfv[4];
        #pragma unroll
        for (int mt = 0; mt < 4; ++mt)
            af[mt] = *(const short8*)&hT[(wm + mt * 16 + fr) * 128 + cswz];
        #pragma unroll
        for (int nt = 0; nt < 4; ++nt) {
            int rr = wn + nt * 16 + fr;
            bfv[nt] = *(const short8*)&Bs[rr * 32 + ((cfrag ^ swzr) << 3)];
        }

        __syncthreads();   // fragment reads complete -> Bs overwrite safe
        if (k0 + 32 < K) {
            gload16(pb0 + k0 + 32, lB0);   // async; drains at next top barrier
            gload16(pb1 + k0 + 32, lB1);
        }

        #pragma unroll
        for (int mt = 0; mt < 4; ++mt)
            #pragma unroll
            for (int nt = 0; nt < 4; ++nt)
                acc[mt][nt] = __builtin_amdgcn_mfma_f32_16x16x32_bf16(
                    af[mt], bfv[nt], acc[mt][nt], 0, 0, 0);
    }

    // ---- epilogue: bias + relu -> bf16 hA (global), old gemm1 value order ----
    #pragma unroll
    for (int mt = 0; mt < 4; ++mt) {
        #pragma unroll
        for (int nt = 0; nt < 4; ++nt) {
            #pragma unroll
            for (int r = 0; r < 4; ++r) {
                int grow = m0 + wm + mt * 16 + (lane >> 4) * 4 + r;
                int gcol = wn + nt * 16 + fr;
                if (grow < M) {
                    float v = acc[mt][nt][r] + b1[gcol];
                    hA[(size_t)grow * 256 + gcol] = f2bf(fmaxf(v, 0.f));
                }
            }
        }
    }
}

// ---------------- fused layer 2: gather + GEMM + classifier (R9 exact) ----------------
// 512 threads / 8 waves (2x4); LDS 80KB (hT/T 64KB + Bs 16KB).
// Phase 1: gather 128 rows of hB into LDS (exact R0 math). Phase 2:
// T = relu(hT @ W2 + b2), B staged via gload16 (pre-issued, overlapped).
// Phase 3: T -> LDS (aliases hT). Phase 4: out = T @ Wc + bc.

__global__ __launch_bounds__(512, 4) void layer2_fused_kernel(
    const short* __restrict__ hA,     // [M,256] bf16 (layer-1 output)
    const int* __restrict__ deg, const int* __restrict__ eslot,
    const short* __restrict__ Wt2,    // [256 cols][256 k] bf16
    const float* __restrict__ b2,
    const short* __restrict__ Wtc,    // [32 cols][256 k] bf16
    const float* __restrict__ bc,
    float* __restrict__ out,          // [M,32] fp32
    int M)
{
    const int K = 256;
    __shared__ short smem[128 * 256 + 256 * 32];   // hT/T 64KB + Bs 16KB = 80KB
    short* hT = smem;
    short* Bs = smem + 128 * 256;

    const int tid = threadIdx.x;
    const int wave = tid >> 6, lane = tid & 63;
    const int m0 = blockIdx.x * 128;

    // ---- B staging geometry (Wt2 rows 0..255, 32 shorts per K-step) ----
    const int srow = tid >> 2;               // 0..127
    const int cdst = tid & 3;
    const int lrB0 = srow, lrB1 = 128 + srow;
    const int cg0 = cdst ^ ((lrB0 >> 1) & 3);
    const int cg1 = cdst ^ ((lrB1 >> 1) & 3);
    const short* pb0 = Wt2 + (size_t)lrB0 * K + cg0 * 8;
    const short* pb1 = Wt2 + (size_t)lrB1 * K + cg1 * 8;
    short* lB0 = &Bs[(wave * 16) * 32];
    short* lB1 = &Bs[(128 + wave * 16) * 32];

    // pre-issue K-step 0 staging (no deps; lands during the gather phase)
    gload16(pb0, lB0);
    gload16(pb1, lB1);

    // ---- Phase 1: gather 128 rows of hB into hT (exact R0 math) ----
    {
        const int grp = tid >> 5;            // 0..15: node group
        const int gl  = tid & 31;            // feature chunk 0..31
        const int f   = gl * 8;
        const int wslot = (gl >> 2) * 32;    // window base (shorts)
        for (int r0 = 0; r0 < 128; r0 += 16) {
            int r = r0 + grp;
            int node = m0 + r; if (node >= M) node = M - 1;
            int dg = deg[node];
            if (dg > CAP) dg = CAP;
            float di = rsqrtf((float)dg + 1.0f);
            float w = di * di;
            short8 hv = *(const short8*)(hA + (size_t)node * 256 + f);
            float a[8];
            #pragma unroll
            for (int j = 0; j < 8; ++j) a[j] = bf2f(hv[j]) * w;

            const int* bucket = eslot + (size_t)node * CAP;
            for (int e = 0; e < dg; e += 4) {
                int4 s4 = *(const int4*)(bucket + e);
                int i0 = s4.x;
                int i1 = (e + 1 < dg) ? s4.y : 0;
                int i2 = (e + 2 < dg) ? s4.z : 0;
                int i3 = (e + 3 < dg) ? s4.w : 0;
                int d0 = deg[i0], d1 = deg[i1], d2 = deg[i2], d3 = deg[i3];
                short8 v0 = *(const short8*)(hA + (size_t)i0 * 256 + f);
                short8 v1 = *(const short8*)(hA + (size_t)i1 * 256 + f);
                short8 v2 = *(const short8*)(hA + (size_t)i2 * 256 + f);
                short8 v3 = *(const short8*)(hA + (size_t)i3 * 256 + f);
                float w0 = rsqrtf((float)d0 + 1.0f) * di;
                float w1 = (e + 1 < dg) ? rsqrtf((float)d1 + 1.0f) * di : 0.f;
                float w2 = (e + 2 < dg) ? rsqrtf((float)d2 + 1.0f) * di : 0.f;
                float w3 = (e + 3 < dg) ? rsqrtf((float)d3 + 1.0f) * di : 0.f;
                #pragma unroll
                for (int j = 0; j < 8; ++j) {
                    a[j] = fmaf(bf2f(v0[j]), w0, a[j]);
                    a[j] = fmaf(bf2f(v1[j]), w1, a[j]);
                    a[j] = fmaf(bf2f(v2[j]), w2, a[j]);
                    a[j] = fmaf(bf2f(v3[j]), w3, a[j]);
                }
            }
            short8 o;
            #pragma unroll
            for (int j = 0; j < 8; ++j) o[j] = f2bf(a[j]);
            int slot = (gl & 3) ^ ((r >> 1) & 3);
            *(short8*)&hT[r * 256 + wslot + slot * 8] = o;
        }
    }

    // ---- Phase 2: T = relu(hT @ W2 + b2), staging overlapped with MFMA ----
    const int wm = (wave >> 2) * 64;         // 0,64
    const int wn = (wave & 3) * 64;          // 0,64,128,192
    const int fr = lane & 15;
    const int cfrag = lane >> 4;
    const int swzr = (fr >> 1) & 3;

    f32x4 acc[4][4] = {};
    for (int k0 = 0; k0 < K; k0 += 32) {
        __syncthreads();   // Bs[k0] resident; hT writes visible (iter 0); prior reads done

        short8 af[4], bfv[4];
        #pragma unroll
        for (int mt = 0; mt < 4; ++mt) {
            int rr = wm + mt * 16 + fr;
            af[mt] = *(const short8*)&hT[rr * 256 + k0 + ((cfrag ^ swzr) << 3)];
        }
        #pragma unroll
        for (int nt = 0; nt < 4; ++nt) {
            int rr = wn + nt * 16 + fr;
            bfv[nt] = *(const short8*)&Bs[rr * 32 + ((cfrag ^ swzr) << 3)];
        }

        __syncthreads();   // fragment reads complete -> Bs overwrite safe
        if (k0 + 32 < K) {
            gload16(pb0 + k0 + 32, lB0);   // async; drains at next top barrier
            gload16(pb1 + k0 + 32, lB1);
        }

        #pragma unroll
        for (int mt = 0; mt < 4; ++mt)
            #pragma unroll
            for (int nt = 0; nt < 4; ++nt)
                acc[mt][nt] = __builtin_amdgcn_mfma_f32_16x16x32_bf16(
                    af[mt], bfv[nt], acc[mt][nt], 0, 0, 0);
    }

    // ---- Phase 3: bias+relu -> bf16 T tile (aliases hT; reads all done) ----
    #pragma unroll
    for (int mt = 0; mt < 4; ++mt) {
        #pragma unroll
        for (int nt = 0; nt < 4; ++nt) {
            #pragma unroll
            for (int r = 0; r < 4; ++r) {
                int lrow = wm + mt * 16 + (lane >> 4) * 4 + r;
                int gcol = wn + nt * 16 + fr;
                float v = acc[mt][nt][r] + b2[gcol];
                int slot = ((gcol >> 3) & 3) ^ ((lrow >> 1) & 3);
                hT[lrow * 256 + (gcol >> 5) * 32 + slot * 8 + (gcol & 7)] =
                    f2bf(fmaxf(v, 0.f));
            }
        }
    }
    __syncthreads();

    // ---- Phase 4: out = T @ Wc + bc (gemmc's exact k-order / C mapping) ----
    f32x4 c2[2] = {};
    for (int k0 = 0; k0 < K; k0 += 32) {
        int row = wave * 16 + fr;
        short8 a8 = *(const short8*)&hT[row * 256 + k0 + ((cfrag ^ swzr) << 3)];
        #pragma unroll
        for (int nt = 0; nt < 2; ++nt) {
            short8 b8 = *(const short8*)(Wtc + (size_t)(nt * 16 + fr) * K +
                                         (cfrag << 3) + k0);
            c2[nt] = __builtin_amdgcn_mfma_f32_16x16x32_bf16(a8, b8, c2[nt], 0, 0, 0);
        }
    }
    #pragma unroll
    for (int nt = 0; nt < 2; ++nt) {
        #pragma unroll
        for (int r = 0; r < 4; ++r) {
            int grow = m0 + wave * 16 + (lane >> 4) * 4 + r;
            int gcol = nt * 16 + fr;
            if (grow < M)
                out[(size_t)grow * 32 + gcol] = c2[nt][r] + bc[gcol];
        }
    }
}

// ---------------- launch ----------------

extern "C" void kernel_launch(void* const* d_in, const int* in_sizes, int n_in,
                              void* d_out, int out_size, void* d_ws, size_t ws_size,
                              hipStream_t stream) {
    const float* x  = (const float*)d_in[0];
    const int*   ei = (const int*)d_in[1];
    const float* W1 = (const float*)d_in[2];
    const float* b1 = (const float*)d_in[3];
    const float* W2 = (const float*)d_in[4];
    const float* b2 = (const float*)d_in[5];
    const float* Wc = (const float*)d_in[6];
    const float* bc = (const float*)d_in[7];
    float* out = (float*)d_out;

    const int E = in_sizes[1] / 2;
    const int N = in_sizes[0] / 128;
    const int* src = ei;
    const int* dst = ei + E;

    // workspace layout (shorts first, 16B aligned)
    short* xb   = (short*)d_ws;                     // N*128
    short* hA   = xb + (size_t)N * 128;             // N*256
    short* Wt1  = hA + (size_t)N * 256;             // 256*128
    short* Wt2  = Wt1 + 256 * 128;                  // 256*256
    short* Wtc  = Wt2 + 256 * 256;                  // 32*256
    int*   deg  = (int*)(Wtc + 32 * 256);           // N
    int*   eslot= deg + N;                          // N*CAP (16B-aligned: N*CAP*4)

    const int TB = 256;

    hipMemsetAsync(deg, 0, (size_t)N * sizeof(int), stream);

    const int prep_total = N * 16 + 128 * 256 + 256 * 256 + 256 * 32 + E;
    prep_kernel<<<(prep_total + TB - 1) / TB, TB, 0, stream>>>(
        x, W1, W2, Wc, src, dst, xb, Wt1, Wt2, Wtc, deg, eslot, N, E);

    const int gy = (N + 127) / 128;

    // layer 1, fully fused: hA = relu((A_hat @ X) @ W1 + b1)
    layer1_fused_kernel<<<gy, 512, 0, stream>>>(
        xb, deg, eslot, Wt1, b1, hA, N);

    // layer 2 + classifier, fully fused (R9 exact):
    //   out = relu((A_hat @ hA) @ W2 + b2) @ Wc + bc
    layer2_fused_kernel<<<gy, 512, 0, stream>>>(
        hA, deg, eslot, Wt2, b2, Wtc, bc, out, N);
}

// Round 16
// 180.138 us; speedup vs baseline: 1.1920x; 1.0116x over previous
//
#include <hip/hip_runtime.h>
#include <math.h>

using short8 = __attribute__((ext_vector_type(8))) short;
using f32x4 = __attribute__((ext_vector_type(4))) float;

#define CAP 48   // edge-bucket capacity; P(Poisson(6) >= 48) ~ 1e-30

__device__ inline short f2bf(float f) {
    unsigned u = __builtin_bit_cast(unsigned, f);
    unsigned r = (u + 0x7fffu + ((u >> 16) & 1u)) >> 16;
    return (short)r;
}
__device__ inline float bf2f(short s) {
    unsigned u = ((unsigned)(unsigned short)s) << 16;
    return __builtin_bit_cast(float, u);
}

// async global->LDS, 16B per lane. Dest is wave-uniform base + lane*16 (HW);
// source address is per-lane (pre-swizzled for bank-conflict-free reads).
typedef const void __attribute__((address_space(1))) gvoid_t;
typedef void __attribute__((address_space(3))) svoid_t;
__device__ inline void gload16(const short* g, short* l) {
    __builtin_amdgcn_global_load_lds((gvoid_t*)g, (svoid_t*)l, 16, 0, 0);
}

// ---------------- fused prep: x->bf16, W transposes, edge bucketing ----------------
// deg[] must be zeroed (memsetAsync) before this kernel. (eslot NOT zeroed;
// gather guards padding indices.)

__global__ void prep_kernel(const float* __restrict__ x, const float* __restrict__ W1,
                            const float* __restrict__ W2, const float* __restrict__ Wc,
                            const int* __restrict__ src, const int* __restrict__ dst,
                            short* __restrict__ xb, short* __restrict__ Wt1,
                            short* __restrict__ Wt2, short* __restrict__ Wtc,
                            int* __restrict__ deg, int* __restrict__ eslot,
                            int n, int e) {
    int idx = blockIdx.x * blockDim.x + threadIdx.x;
    const int nx8 = n * 16;                      // N*128/8 groups of 8
    if (idx < nx8) {
        const float4* p = (const float4*)x + (size_t)idx * 2;
        float4 v0 = p[0], v1 = p[1];
        short8 o;
        o[0] = f2bf(v0.x); o[1] = f2bf(v0.y); o[2] = f2bf(v0.z); o[3] = f2bf(v0.w);
        o[4] = f2bf(v1.x); o[5] = f2bf(v1.y); o[6] = f2bf(v1.z); o[7] = f2bf(v1.w);
        ((short8*)xb)[idx] = o;
        return;
    }
    idx -= nx8;
    if (idx < 128 * 256) {                       // W1: K=128, N=256
        int k = idx >> 8, c = idx & 255;
        Wt1[c * 128 + k] = f2bf(W1[idx]);
        return;
    }
    idx -= 128 * 256;
    if (idx < 256 * 256) {                       // W2: K=256, N=256
        int k = idx >> 8, c = idx & 255;
        Wt2[c * 256 + k] = f2bf(W2[idx]);
        return;
    }
    idx -= 256 * 256;
    if (idx < 256 * 32) {                        // Wc: K=256, N=32
        int k = idx >> 5, c = idx & 31;
        Wtc[c * 256 + k] = f2bf(Wc[idx]);
        return;
    }
    idx -= 256 * 32;
    if (idx < e) {                               // edge bucketing
        int d = dst[idx], s = src[idx];
        int pos = atomicAdd(&deg[d], 1);
        if (pos < CAP) eslot[(size_t)d * CAP + pos] = s;
    }
}

// ---------------- fused layer 1: gather + GEMM (K=128) ----------------
// 512 threads / 8 waves. Phase 1 (PEELED): per row, bucket[0..15] (4x int4),
// deg[node], and the self row all issue together (no mutual deps); round 0
// covers slots 0..7 unconditionally with weight-guards (fmaf(v,0,a)=a ->
// bitwise-identical); round 1 under if(dg>8); rare 4-wide tail deg>16.
// Rationale: the fused kernel is hard-capped at 8 waves/CU (R10-R14), so
// per-wave ILP is free here (R1/R2's occupancy objection doesn't apply).
// Phase 2: hA = relu(hT @ W1 + b1), staged-B loop (R9 pattern), K=128.

__global__ __launch_bounds__(512, 4) void layer1_fused_kernel(
    const short* __restrict__ xb,     // [M,128] bf16
    const int* __restrict__ deg, const int* __restrict__ eslot,
    const short* __restrict__ Wt1,    // [256 cols][128 k] bf16
    const float* __restrict__ b1,
    short* __restrict__ hA,           // [M,256] bf16 out
    int M)
{
    const int K = 128;
    __shared__ short hT[128 * 128];          // 32 KB
    __shared__ short Bs[256 * 32];           // 16 KB (one K-step of Wt1)

    const int tid = threadIdx.x;
    const int wave = tid >> 6, lane = tid & 63;
    const int m0 = blockIdx.x * 128;

    // ---- B staging geometry (Wt1 rows 0..255, 32 shorts per K-step) ----
    const int srow = tid >> 2;               // 0..127
    const int cdst = tid & 3;
    const int lrB0 = srow, lrB1 = 128 + srow;
    const int cg0 = cdst ^ ((lrB0 >> 1) & 3);
    const int cg1 = cdst ^ ((lrB1 >> 1) & 3);
    const short* pb0 = Wt1 + (size_t)lrB0 * K + cg0 * 8;
    const short* pb1 = Wt1 + (size_t)lrB1 * K + cg1 * 8;
    short* lB0 = &Bs[(wave * 16) * 32];
    short* lB1 = &Bs[(128 + wave * 16) * 32];

    // pre-issue K-step 0 staging (no deps; lands during the gather phase)
    gload16(pb0, lB0);
    gload16(pb1, lB1);

    // ---- Phase 1 (peeled): gather 128 rows of aggX into hT (F=128) ----
    {
        const int grp = tid >> 4;            // 0..31: node group
        const int gl  = tid & 15;            // feature chunk 0..15
        const int f   = gl * 8;
        for (int r0 = 0; r0 < 128; r0 += 32) {   // 4 iterations
            int r = r0 + grp;
            int node = m0 + r; if (node >= M) node = M - 1;
            // all row-entry loads issue together: bucket x4, deg, self row
            const int* bucket = eslot + (size_t)node * CAP;
            int4 sa = *(const int4*)(bucket + 0);
            int4 sb = *(const int4*)(bucket + 4);
            int4 sc = *(const int4*)(bucket + 8);
            int4 sd = *(const int4*)(bucket + 12);
            int dg = deg[node];
            short8 hv = *(const short8*)(xb + (size_t)node * 128 + f);
            if (dg > CAP) dg = CAP;
            float di = rsqrtf((float)dg + 1.0f);
            float w = di * di;
            float a[8];
            #pragma unroll
            for (int j = 0; j < 8; ++j) a[j] = bf2f(hv[j]) * w;

            // round 0: slots 0..7 unconditional (guards -> index 0 / weight 0)
            int id[8];
            id[0] = (0 < dg) ? sa.x : 0;
            id[1] = (1 < dg) ? sa.y : 0;
            id[2] = (2 < dg) ? sa.z : 0;
            id[3] = (3 < dg) ? sa.w : 0;
            id[4] = (4 < dg) ? sb.x : 0;
            id[5] = (5 < dg) ? sb.y : 0;
            id[6] = (6 < dg) ? sb.z : 0;
            id[7] = (7 < dg) ? sb.w : 0;
            short8 v[8];
            int dd[8];
            #pragma unroll
            for (int t = 0; t < 8; ++t) {
                v[t] = *(const short8*)(xb + (size_t)id[t] * 128 + f);
                dd[t] = deg[id[t]];
            }
            float wg[8];
            #pragma unroll
            for (int t = 0; t < 8; ++t)
                wg[t] = (t < dg) ? rsqrtf((float)dd[t] + 1.0f) * di : 0.f;
            #pragma unroll
            for (int t = 0; t < 8; ++t)
                #pragma unroll
                for (int j = 0; j < 8; ++j)
                    a[j] = fmaf(bf2f(v[t][j]), wg[t], a[j]);

            // round 1: slots 8..15 (~16% of rows)
            if (dg > 8) {
                int id1[8];
                id1[0] = sc.x;
                id1[1] = (9  < dg) ? sc.y : 0;
                id1[2] = (10 < dg) ? sc.z : 0;
                id1[3] = (11 < dg) ? sc.w : 0;
                id1[4] = (12 < dg) ? sd.x : 0;
                id1[5] = (13 < dg) ? sd.y : 0;
                id1[6] = (14 < dg) ? sd.z : 0;
                id1[7] = (15 < dg) ? sd.w : 0;
                short8 v1[8];
                int dd1[8];
                #pragma unroll
                for (int t = 0; t < 8; ++t) {
                    v1[t] = *(const short8*)(xb + (size_t)id1[t] * 128 + f);
                    dd1[t] = deg[id1[t]];
                }
                float wg1[8];
                #pragma unroll
                for (int t = 0; t < 8; ++t)
                    wg1[t] = (8 + t < dg) ? rsqrtf((float)dd1[t] + 1.0f) * di : 0.f;
                #pragma unroll
                for (int t = 0; t < 8; ++t)
                    #pragma unroll
                    for (int j = 0; j < 8; ++j)
                        a[j] = fmaf(bf2f(v1[t][j]), wg1[t], a[j]);

                // rare tail: deg > 16 (P ~ 2.5e-4), original 4-wide loop
                for (int e = 16; e < dg; e += 4) {
                    int4 s4 = *(const int4*)(bucket + e);
                    int i0 = s4.x;
                    int i1 = (e + 1 < dg) ? s4.y : 0;
                    int i2 = (e + 2 < dg) ? s4.z : 0;
                    int i3 = (e + 3 < dg) ? s4.w : 0;
                    int d0 = deg[i0], d1 = deg[i1], d2 = deg[i2], d3 = deg[i3];
                    short8 u0 = *(const short8*)(xb + (size_t)i0 * 128 + f);
                    short8 u1 = *(const short8*)(xb + (size_t)i1 * 128 + f);
                    short8 u2 = *(const short8*)(xb + (size_t)i2 * 128 + f);
                    short8 u3 = *(const short8*)(xb + (size_t)i3 * 128 + f);
                    float w0 = rsqrtf((float)d0 + 1.0f) * di;
                    float w1 = (e + 1 < dg) ? rsqrtf((float)d1 + 1.0f) * di : 0.f;
                    float w2 = (e + 2 < dg) ? rsqrtf((float)d2 + 1.0f) * di : 0.f;
                    float w3 = (e + 3 < dg) ? rsqrtf((float)d3 + 1.0f) * di : 0.f;
                    #pragma unroll
                    for (int j = 0; j < 8; ++j) {
                        a[j] = fmaf(bf2f(u0[j]), w0, a[j]);
                        a[j] = fmaf(bf2f(u1[j]), w1, a[j]);
                        a[j] = fmaf(bf2f(u2[j]), w2, a[j]);
                        a[j] = fmaf(bf2f(u3[j]), w3, a[j]);
                    }
                }
            }
            short8 o;
            #pragma unroll
            for (int j = 0; j < 8; ++j) o[j] = f2bf(a[j]);
            *(short8*)&hT[r * 128 + ((gl ^ (r & 7)) << 3)] = o;   // swizzled chunk
        }
    }

    // ---- Phase 2: hA = relu(hT @ W1 + b1); staged-B loop; K=128 ----
    const int wm = (wave >> 2) * 64;         // 0,64
    const int wn = (wave & 3) * 64;          // 0,64,128,192
    const int fr = lane & 15;
    const int cfrag = lane >> 4;
    const int rk = fr & 7;                   // hT swizzle key (wave rows +16k)
    const int swzr = (fr >> 1) & 3;          // Bs swizzle key (R9 pattern)

    f32x4 acc[4][4] = {};
    for (int k0 = 0; k0 < K; k0 += 32) {
        __syncthreads();   // Bs[k0] resident; hT writes visible (iter 0); prior reads done

        const int cswz = (((k0 >> 3) + cfrag) ^ rk) << 3;   // hT swizzled chunk offset
        short8 af[4], bfv[4];
        #pragma unroll
        for (int mt = 0; mt < 4; ++mt)
            af[mt] = *(const short8*)&hT[(wm + mt * 16 + fr) * 128 + cswz];
        #pragma unroll
        for (int nt = 0; nt < 4; ++nt) {
            int rr = wn + nt * 16 + fr;
            bfv[nt] = *(const short8*)&Bs[rr * 32 + ((cfrag ^ swzr) << 3)];
        }

        __syncthreads();   // fragment reads complete -> Bs overwrite safe
        if (k0 + 32 < K) {
            gload16(pb0 + k0 + 32, lB0);   // async; drains at next top barrier
            gload16(pb1 + k0 + 32, lB1);
        }

        #pragma unroll
        for (int mt = 0; mt < 4; ++mt)
            #pragma unroll
            for (int nt = 0; nt < 4; ++nt)
                acc[mt][nt] = __builtin_amdgcn_mfma_f32_16x16x32_bf16(
                    af[mt], bfv[nt], acc[mt][nt], 0, 0, 0);
    }

    // ---- epilogue: bias + relu -> bf16 hA (global), old gemm1 value order ----
    #pragma unroll
    for (int mt = 0; mt < 4; ++mt) {
        #pragma unroll
        for (int nt = 0; nt < 4; ++nt) {
            #pragma unroll
            for (int r = 0; r < 4; ++r) {
                int grow = m0 + wm + mt * 16 + (lane >> 4) * 4 + r;
                int gcol = wn + nt * 16 + fr;
                if (grow < M) {
                    float v = acc[mt][nt][r] + b1[gcol];
                    hA[(size_t)grow * 256 + gcol] = f2bf(fmaxf(v, 0.f));
                }
            }
        }
    }
}

// ---------------- fused layer 2: gather + GEMM + classifier ----------------
// R15 structure; Phase 1 peeled like layer 1 (see rationale there).

__global__ __launch_bounds__(512, 4) void layer2_fused_kernel(
    const short* __restrict__ hA,     // [M,256] bf16 (layer-1 output)
    const int* __restrict__ deg, const int* __restrict__ eslot,
    const short* __restrict__ Wt2,    // [256 cols][256 k] bf16
    const float* __restrict__ b2,
    const short* __restrict__ Wtc,    // [32 cols][256 k] bf16
    const float* __restrict__ bc,
    float* __restrict__ out,          // [M,32] fp32
    int M)
{
    const int K = 256;
    __shared__ short smem[128 * 256 + 256 * 32];   // hT/T 64KB + Bs 16KB = 80KB
    short* hT = smem;
    short* Bs = smem + 128 * 256;

    const int tid = threadIdx.x;
    const int wave = tid >> 6, lane = tid & 63;
    const int m0 = blockIdx.x * 128;

    // ---- B staging geometry (Wt2 rows 0..255, 32 shorts per K-step) ----
    const int srow = tid >> 2;               // 0..127
    const int cdst = tid & 3;
    const int lrB0 = srow, lrB1 = 128 + srow;
    const int cg0 = cdst ^ ((lrB0 >> 1) & 3);
    const int cg1 = cdst ^ ((lrB1 >> 1) & 3);
    const short* pb0 = Wt2 + (size_t)lrB0 * K + cg0 * 8;
    const short* pb1 = Wt2 + (size_t)lrB1 * K + cg1 * 8;
    short* lB0 = &Bs[(wave * 16) * 32];
    short* lB1 = &Bs[(128 + wave * 16) * 32];

    // pre-issue K-step 0 staging (no deps; lands during the gather phase)
    gload16(pb0, lB0);
    gload16(pb1, lB1);

    // ---- Phase 1 (peeled): gather 128 rows of hB into hT (F=256) ----
    {
        const int grp = tid >> 5;            // 0..15: node group
        const int gl  = tid & 31;            // feature chunk 0..31
        const int f   = gl * 8;
        const int wslot = (gl >> 2) * 32;    // window base (shorts)
        for (int r0 = 0; r0 < 128; r0 += 16) {
            int r = r0 + grp;
            int node = m0 + r; if (node >= M) node = M - 1;
            const int* bucket = eslot + (size_t)node * CAP;
            int4 sa = *(const int4*)(bucket + 0);
            int4 sb = *(const int4*)(bucket + 4);
            int4 sc = *(const int4*)(bucket + 8);
            int4 sd = *(const int4*)(bucket + 12);
            int dg = deg[node];
            short8 hv = *(const short8*)(hA + (size_t)node * 256 + f);
            if (dg > CAP) dg = CAP;
            float di = rsqrtf((float)dg + 1.0f);
            float w = di * di;
            float a[8];
            #pragma unroll
            for (int j = 0; j < 8; ++j) a[j] = bf2f(hv[j]) * w;

            // round 0: slots 0..7 unconditional (guards -> index 0 / weight 0)
            int id[8];
            id[0] = (0 < dg) ? sa.x : 0;
            id[1] = (1 < dg) ? sa.y : 0;
            id[2] = (2 < dg) ? sa.z : 0;
            id[3] = (3 < dg) ? sa.w : 0;
            id[4] = (4 < dg) ? sb.x : 0;
            id[5] = (5 < dg) ? sb.y : 0;
            id[6] = (6 < dg) ? sb.z : 0;
            id[7] = (7 < dg) ? sb.w : 0;
            short8 v[8];
            int dd[8];
            #pragma unroll
            for (int t = 0; t < 8; ++t) {
                v[t] = *(const short8*)(hA + (size_t)id[t] * 256 + f);
                dd[t] = deg[id[t]];
            }
            float wg[8];
            #pragma unroll
            for (int t = 0; t < 8; ++t)
                wg[t] = (t < dg) ? rsqrtf((float)dd[t] + 1.0f) * di : 0.f;
            #pragma unroll
            for (int t = 0; t < 8; ++t)
                #pragma unroll
                for (int j = 0; j < 8; ++j)
                    a[j] = fmaf(bf2f(v[t][j]), wg[t], a[j]);

            // round 1: slots 8..15 (~16% of rows)
            if (dg > 8) {
                int id1[8];
                id1[0] = sc.x;
                id1[1] = (9  < dg) ? sc.y : 0;
                id1[2] = (10 < dg) ? sc.z : 0;
                id1[3] = (11 < dg) ? sc.w : 0;
                id1[4] = (12 < dg) ? sd.x : 0;
                id1[5] = (13 < dg) ? sd.y : 0;
                id1[6] = (14 < dg) ? sd.z : 0;
                id1[7] = (15 < dg) ? sd.w : 0;
                short8 v1[8];
                int dd1[8];
                #pragma unroll
                for (int t = 0; t < 8; ++t) {
                    v1[t] = *(const short8*)(hA + (size_t)id1[t] * 256 + f);
                    dd1[t] = deg[id1[t]];
                }
                float wg1[8];
                #pragma unroll
                for (int t = 0; t < 8; ++t)
                    wg1[t] = (8 + t < dg) ? rsqrtf((float)dd1[t] + 1.0f) * di : 0.f;
                #pragma unroll
                for (int t = 0; t < 8; ++t)
                    #pragma unroll
                    for (int j = 0; j < 8; ++j)
                        a[j] = fmaf(bf2f(v1[t][j]), wg1[t], a[j]);

                // rare tail: deg > 16 (P ~ 2.5e-4), original 4-wide loop
                for (int e = 16; e < dg; e += 4) {
                    int4 s4 = *(const int4*)(bucket + e);
                    int i0 = s4.x;
                    int i1 = (e + 1 < dg) ? s4.y : 0;
                    int i2 = (e + 2 < dg) ? s4.z : 0;
                    int i3 = (e + 3 < dg) ? s4.w : 0;
                    int d0 = deg[i0], d1 = deg[i1], d2 = deg[i2], d3 = deg[i3];
                    short8 u0 = *(const short8*)(hA + (size_t)i0 * 256 + f);
                    short8 u1 = *(const short8*)(hA + (size_t)i1 * 256 + f);
                    short8 u2 = *(const short8*)(hA + (size_t)i2 * 256 + f);
                    short8 u3 = *(const short8*)(hA + (size_t)i3 * 256 + f);
                    float w0 = rsqrtf((float)d0 + 1.0f) * di;
                    float w1 = (e + 1 < dg) ? rsqrtf((float)d1 + 1.0f) * di : 0.f;
                    float w2 = (e + 2 < dg) ? rsqrtf((float)d2 + 1.0f) * di : 0.f;
                    float w3 = (e + 3 < dg) ? rsqrtf((float)d3 + 1.0f) * di : 0.f;
                    #pragma unroll
                    for (int j = 0; j < 8; ++j) {
                        a[j] = fmaf(bf2f(u0[j]), w0, a[j]);
                        a[j] = fmaf(bf2f(u1[j]), w1, a[j]);
                        a[j] = fmaf(bf2f(u2[j]), w2, a[j]);
                        a[j] = fmaf(bf2f(u3[j]), w3, a[j]);
                    }
                }
            }
            short8 o;
            #pragma unroll
            for (int j = 0; j < 8; ++j) o[j] = f2bf(a[j]);
            int slot = (gl & 3) ^ ((r >> 1) & 3);
            *(short8*)&hT[r * 256 + wslot + slot * 8] = o;
        }
    }

    // ---- Phase 2: T = relu(hT @ W2 + b2), staging overlapped with MFMA ----
    const int wm = (wave >> 2) * 64;         // 0,64
    const int wn = (wave & 3) * 64;          // 0,64,128,192
    const int fr = lane & 15;
    const int cfrag = lane >> 4;
    const int swzr = (fr >> 1) & 3;

    f32x4 acc[4][4] = {};
    for (int k0 = 0; k0 < K; k0 += 32) {
        __syncthreads();   // Bs[k0] resident; hT writes visible (iter 0); prior reads done

        short8 af[4], bfv[4];
        #pragma unroll
        for (int mt = 0; mt < 4; ++mt) {
            int rr = wm + mt * 16 + fr;
            af[mt] = *(const short8*)&hT[rr * 256 + k0 + ((cfrag ^ swzr) << 3)];
        }
        #pragma unroll
        for (int nt = 0; nt < 4; ++nt) {
            int rr = wn + nt * 16 + fr;
            bfv[nt] = *(const short8*)&Bs[rr * 32 + ((cfrag ^ swzr) << 3)];
        }

        __syncthreads();   // fragment reads complete -> Bs overwrite safe
        if (k0 + 32 < K) {
            gload16(pb0 + k0 + 32, lB0);   // async; drains at next top barrier
            gload16(pb1 + k0 + 32, lB1);
        }

        #pragma unroll
        for (int mt = 0; mt < 4; ++mt)
            #pragma unroll
            for (int nt = 0; nt < 4; ++nt)
                acc[mt][nt] = __builtin_amdgcn_mfma_f32_16x16x32_bf16(
                    af[mt], bfv[nt], acc[mt][nt], 0, 0, 0);
    }

    // ---- Phase 3: bias+relu -> bf16 T tile (aliases hT; reads all done) ----
    #pragma unroll
    for (int mt = 0; mt < 4; ++mt) {
        #pragma unroll
        for (int nt = 0; nt < 4; ++nt) {
            #pragma unroll
            for (int r = 0; r < 4; ++r) {
                int lrow = wm + mt * 16 + (lane >> 4) * 4 + r;
                int gcol = wn + nt * 16 + fr;
                float v = acc[mt][nt][r] + b2[gcol];
                int slot = ((gcol >> 3) & 3) ^ ((lrow >> 1) & 3);
                hT[lrow * 256 + (gcol >> 5) * 32 + slot * 8 + (gcol & 7)] =
                    f2bf(fmaxf(v, 0.f));
            }
        }
    }
    __syncthreads();

    // ---- Phase 4: out = T @ Wc + bc (gemmc's exact k-order / C mapping) ----
    f32x4 c2[2] = {};
    for (int k0 = 0; k0 < K; k0 += 32) {
        int row = wave * 16 + fr;
        short8 a8 = *(const short8*)&hT[row * 256 + k0 + ((cfrag ^ swzr) << 3)];
        #pragma unroll
        for (int nt = 0; nt < 2; ++nt) {
            short8 b8 = *(const short8*)(Wtc + (size_t)(nt * 16 + fr) * K +
                                         (cfrag << 3) + k0);
            c2[nt] = __builtin_amdgcn_mfma_f32_16x16x32_bf16(a8, b8, c2[nt], 0, 0, 0);
        }
    }
    #pragma unroll
    for (int nt = 0; nt < 2; ++nt) {
        #pragma unroll
        for (int r = 0; r < 4; ++r) {
            int grow = m0 + wave * 16 + (lane >> 4) * 4 + r;
            int gcol = nt * 16 + fr;
            if (grow < M)
                out[(size_t)grow * 32 + gcol] = c2[nt][r] + bc[gcol];
        }
    }
}

// ---------------- launch ----------------

extern "C" void kernel_launch(void* const* d_in, const int* in_sizes, int n_in,
                              void* d_out, int out_size, void* d_ws, size_t ws_size,
                              hipStream_t stream) {
    const float* x  = (const float*)d_in[0];
    const int*   ei = (const int*)d_in[1];
    const float* W1 = (const float*)d_in[2];
    const float* b1 = (const float*)d_in[3];
    const float* W2 = (const float*)d_in[4];
    const float* b2 = (const float*)d_in[5];
    const float* Wc = (const float*)d_in[6];
    const float* bc = (const float*)d_in[7];
    float* out = (float*)d_out;

    const int E = in_sizes[1] / 2;
    const int N = in_sizes[0] / 128;
    const int* src = ei;
    const int* dst = ei + E;

    // workspace layout (shorts first, 16B aligned)
    short* xb   = (short*)d_ws;                     // N*128
    short* hA   = xb + (size_t)N * 128;             // N*256
    short* Wt1  = hA + (size_t)N * 256;             // 256*128
    short* Wt2  = Wt1 + 256 * 128;                  // 256*256
    short* Wtc  = Wt2 + 256 * 256;                  // 32*256
    int*   deg  = (int*)(Wtc + 32 * 256);           // N
    int*   eslot= deg + N;                          // N*CAP (16B-aligned: N*CAP*4)

    const int TB = 256;

    hipMemsetAsync(deg, 0, (size_t)N * sizeof(int), stream);

    const int prep_total = N * 16 + 128 * 256 + 256 * 256 + 256 * 32 + E;
    prep_kernel<<<(prep_total + TB - 1) / TB, TB, 0, stream>>>(
        x, W1, W2, Wc, src, dst, xb, Wt1, Wt2, Wtc, deg, eslot, N, E);

    const int gy = (N + 127) / 128;

    // layer 1, fully fused: hA = relu((A_hat @ X) @ W1 + b1)
    layer1_fused_kernel<<<gy, 512, 0, stream>>>(
        xb, deg, eslot, Wt1, b1, hA, N);

    // layer 2 + classifier, fully fused:
    //   out = relu((A_hat @ hA) @ W2 + b2) @ Wc + bc
    layer2_fused_kernel<<<gy, 512, 0, stream>>>(
        hA, deg, eslot, Wt2, b2, Wtc, bc, out, N);
}

// Round 17
// 178.997 us; speedup vs baseline: 1.1996x; 1.0064x over previous
//
#include <hip/hip_runtime.h>
#include <math.h>

using short8 = __attribute__((ext_vector_type(8))) short;
using f32x4 = __attribute__((ext_vector_type(4))) float;

#define CAP 48   // edge-bucket capacity; P(Poisson(6) >= 48) ~ 1e-30

__device__ inline short f2bf(float f) {
    unsigned u = __builtin_bit_cast(unsigned, f);
    unsigned r = (u + 0x7fffu + ((u >> 16) & 1u)) >> 16;
    return (short)r;
}
__device__ inline float bf2f(short s) {
    unsigned u = ((unsigned)(unsigned short)s) << 16;
    return __builtin_bit_cast(float, u);
}

// async global->LDS, 16B per lane. Dest is wave-uniform base + lane*16 (HW);
// source address is per-lane (pre-swizzled for bank-conflict-free reads).
typedef const void __attribute__((address_space(1))) gvoid_t;
typedef void __attribute__((address_space(3))) svoid_t;
__device__ inline void gload16(const short* g, short* l) {
    __builtin_amdgcn_global_load_lds((gvoid_t*)g, (svoid_t*)l, 16, 0, 0);
}

// ---------------- fused prep: x->bf16, W transposes, edge bucketing ----------------
// deg[] must be zeroed (memsetAsync) before this kernel. (eslot NOT zeroed;
// gather guards padding indices.)

__global__ void prep_kernel(const float* __restrict__ x, const float* __restrict__ W1,
                            const float* __restrict__ W2, const float* __restrict__ Wc,
                            const int* __restrict__ src, const int* __restrict__ dst,
                            short* __restrict__ xb, short* __restrict__ Wt1,
                            short* __restrict__ Wt2, short* __restrict__ Wtc,
                            int* __restrict__ deg, int* __restrict__ eslot,
                            int n, int e) {
    int idx = blockIdx.x * blockDim.x + threadIdx.x;
    const int nx8 = n * 16;                      // N*128/8 groups of 8
    if (idx < nx8) {
        const float4* p = (const float4*)x + (size_t)idx * 2;
        float4 v0 = p[0], v1 = p[1];
        short8 o;
        o[0] = f2bf(v0.x); o[1] = f2bf(v0.y); o[2] = f2bf(v0.z); o[3] = f2bf(v0.w);
        o[4] = f2bf(v1.x); o[5] = f2bf(v1.y); o[6] = f2bf(v1.z); o[7] = f2bf(v1.w);
        ((short8*)xb)[idx] = o;
        return;
    }
    idx -= nx8;
    if (idx < 128 * 256) {                       // W1: K=128, N=256
        int k = idx >> 8, c = idx & 255;
        Wt1[c * 128 + k] = f2bf(W1[idx]);
        return;
    }
    idx -= 128 * 256;
    if (idx < 256 * 256) {                       // W2: K=256, N=256
        int k = idx >> 8, c = idx & 255;
        Wt2[c * 256 + k] = f2bf(W2[idx]);
        return;
    }
    idx -= 256 * 256;
    if (idx < 256 * 32) {                        // Wc: K=256, N=32
        int k = idx >> 5, c = idx & 31;
        Wtc[c * 256 + k] = f2bf(Wc[idx]);
        return;
    }
    idx -= 256 * 32;
    if (idx < e) {                               // edge bucketing
        int d = dst[idx], s = src[idx];
        int pos = atomicAdd(&deg[d], 1);
        if (pos < CAP) eslot[(size_t)d * CAP + pos] = s;
    }
}

// ---------------- fused layer 1: gather + GEMM (K=128) ----------------
// 512 threads / 8 waves. Phase 1 (peeled): per row, bucket[0..15] (4x int4),
// deg[node], and the self row all issue together; round 0 covers slots 0..7
// unconditionally with weight-guards (fmaf(v,0,a)=a -> bitwise-identical);
// round 1 under if(dg>8); rare 4-wide tail deg>16.
// Phase 2: hA = relu(hT @ W1 + b1), staged-B loop, K=128.

__global__ __launch_bounds__(512, 4) void layer1_fused_kernel(
    const short* __restrict__ xb,     // [M,128] bf16
    const int* __restrict__ deg, const int* __restrict__ eslot,
    const short* __restrict__ Wt1,    // [256 cols][128 k] bf16
    const float* __restrict__ b1,
    short* __restrict__ hA,           // [M,256] bf16 out
    int M)
{
    const int K = 128;
    __shared__ short hT[128 * 128];          // 32 KB
    __shared__ short Bs[256 * 32];           // 16 KB (one K-step of Wt1)

    const int tid = threadIdx.x;
    const int wave = tid >> 6, lane = tid & 63;
    const int m0 = blockIdx.x * 128;

    // ---- B staging geometry (Wt1 rows 0..255, 32 shorts per K-step) ----
    const int srow = tid >> 2;               // 0..127
    const int cdst = tid & 3;
    const int lrB0 = srow, lrB1 = 128 + srow;
    const int cg0 = cdst ^ ((lrB0 >> 1) & 3);
    const int cg1 = cdst ^ ((lrB1 >> 1) & 3);
    const short* pb0 = Wt1 + (size_t)lrB0 * K + cg0 * 8;
    const short* pb1 = Wt1 + (size_t)lrB1 * K + cg1 * 8;
    short* lB0 = &Bs[(wave * 16) * 32];
    short* lB1 = &Bs[(128 + wave * 16) * 32];

    // pre-issue K-step 0 staging (no deps; lands during the gather phase)
    gload16(pb0, lB0);
    gload16(pb1, lB1);

    // ---- Phase 1 (peeled): gather 128 rows of aggX into hT (F=128) ----
    {
        const int grp = tid >> 4;            // 0..31: node group
        const int gl  = tid & 15;            // feature chunk 0..15
        const int f   = gl * 8;
        for (int r0 = 0; r0 < 128; r0 += 32) {   // 4 iterations
            int r = r0 + grp;
            int node = m0 + r; if (node >= M) node = M - 1;
            // all row-entry loads issue together: bucket x4, deg, self row
            const int* bucket = eslot + (size_t)node * CAP;
            int4 sa = *(const int4*)(bucket + 0);
            int4 sb = *(const int4*)(bucket + 4);
            int4 sc = *(const int4*)(bucket + 8);
            int4 sd = *(const int4*)(bucket + 12);
            int dg = deg[node];
            short8 hv = *(const short8*)(xb + (size_t)node * 128 + f);
            if (dg > CAP) dg = CAP;
            float di = rsqrtf((float)dg + 1.0f);
            float w = di * di;
            float a[8];
            #pragma unroll
            for (int j = 0; j < 8; ++j) a[j] = bf2f(hv[j]) * w;

            // round 0: slots 0..7 unconditional (guards -> index 0 / weight 0)
            int id[8];
            id[0] = (0 < dg) ? sa.x : 0;
            id[1] = (1 < dg) ? sa.y : 0;
            id[2] = (2 < dg) ? sa.z : 0;
            id[3] = (3 < dg) ? sa.w : 0;
            id[4] = (4 < dg) ? sb.x : 0;
            id[5] = (5 < dg) ? sb.y : 0;
            id[6] = (6 < dg) ? sb.z : 0;
            id[7] = (7 < dg) ? sb.w : 0;
            short8 v[8];
            int dd[8];
            #pragma unroll
            for (int t = 0; t < 8; ++t) {
                v[t] = *(const short8*)(xb + (size_t)id[t] * 128 + f);
                dd[t] = deg[id[t]];
            }
            float wg[8];
            #pragma unroll
            for (int t = 0; t < 8; ++t)
                wg[t] = (t < dg) ? rsqrtf((float)dd[t] + 1.0f) * di : 0.f;
            #pragma unroll
            for (int t = 0; t < 8; ++t)
                #pragma unroll
                for (int j = 0; j < 8; ++j)
                    a[j] = fmaf(bf2f(v[t][j]), wg[t], a[j]);

            // round 1: slots 8..15 (~16% of rows)
            if (dg > 8) {
                int id1[8];
                id1[0] = sc.x;
                id1[1] = (9  < dg) ? sc.y : 0;
                id1[2] = (10 < dg) ? sc.z : 0;
                id1[3] = (11 < dg) ? sc.w : 0;
                id1[4] = (12 < dg) ? sd.x : 0;
                id1[5] = (13 < dg) ? sd.y : 0;
                id1[6] = (14 < dg) ? sd.z : 0;
                id1[7] = (15 < dg) ? sd.w : 0;
                short8 v1[8];
                int dd1[8];
                #pragma unroll
                for (int t = 0; t < 8; ++t) {
                    v1[t] = *(const short8*)(xb + (size_t)id1[t] * 128 + f);
                    dd1[t] = deg[id1[t]];
                }
                float wg1[8];
                #pragma unroll
                for (int t = 0; t < 8; ++t)
                    wg1[t] = (8 + t < dg) ? rsqrtf((float)dd1[t] + 1.0f) * di : 0.f;
                #pragma unroll
                for (int t = 0; t < 8; ++t)
                    #pragma unroll
                    for (int j = 0; j < 8; ++j)
                        a[j] = fmaf(bf2f(v1[t][j]), wg1[t], a[j]);

                // rare tail: deg > 16 (P ~ 2.5e-4), original 4-wide loop
                for (int e = 16; e < dg; e += 4) {
                    int4 s4 = *(const int4*)(bucket + e);
                    int i0 = s4.x;
                    int i1 = (e + 1 < dg) ? s4.y : 0;
                    int i2 = (e + 2 < dg) ? s4.z : 0;
                    int i3 = (e + 3 < dg) ? s4.w : 0;
                    int d0 = deg[i0], d1 = deg[i1], d2 = deg[i2], d3 = deg[i3];
                    short8 u0 = *(const short8*)(xb + (size_t)i0 * 128 + f);
                    short8 u1 = *(const short8*)(xb + (size_t)i1 * 128 + f);
                    short8 u2 = *(const short8*)(xb + (size_t)i2 * 128 + f);
                    short8 u3 = *(const short8*)(xb + (size_t)i3 * 128 + f);
                    float w0 = rsqrtf((float)d0 + 1.0f) * di;
                    float w1 = (e + 1 < dg) ? rsqrtf((float)d1 + 1.0f) * di : 0.f;
                    float w2 = (e + 2 < dg) ? rsqrtf((float)d2 + 1.0f) * di : 0.f;
                    float w3 = (e + 3 < dg) ? rsqrtf((float)d3 + 1.0f) * di : 0.f;
                    #pragma unroll
                    for (int j = 0; j < 8; ++j) {
                        a[j] = fmaf(bf2f(u0[j]), w0, a[j]);
                        a[j] = fmaf(bf2f(u1[j]), w1, a[j]);
                        a[j] = fmaf(bf2f(u2[j]), w2, a[j]);
                        a[j] = fmaf(bf2f(u3[j]), w3, a[j]);
                    }
                }
            }
            short8 o;
            #pragma unroll
            for (int j = 0; j < 8; ++j) o[j] = f2bf(a[j]);
            *(short8*)&hT[r * 128 + ((gl ^ (r & 7)) << 3)] = o;   // swizzled chunk
        }
    }

    // ---- Phase 2: hA = relu(hT @ W1 + b1); staged-B loop; K=128 ----
    const int wm = (wave >> 2) * 64;         // 0,64
    const int wn = (wave & 3) * 64;          // 0,64,128,192
    const int fr = lane & 15;
    const int cfrag = lane >> 4;
    const int rk = fr & 7;                   // hT swizzle key (wave rows +16k)
    const int swzr = (fr >> 1) & 3;          // Bs swizzle key

    f32x4 acc[4][4] = {};
    for (int k0 = 0; k0 < K; k0 += 32) {
        __syncthreads();   // Bs[k0] resident; hT writes visible (iter 0); prior reads done

        const int cswz = (((k0 >> 3) + cfrag) ^ rk) << 3;   // hT swizzled chunk offset
        short8 af[4], bfv[4];
        #pragma unroll
        for (int mt = 0; mt < 4; ++mt)
            af[mt] = *(const short8*)&hT[(wm + mt * 16 + fr) * 128 + cswz];
        #pragma unroll
        for (int nt = 0; nt < 4; ++nt) {
            int rr = wn + nt * 16 + fr;
            bfv[nt] = *(const short8*)&Bs[rr * 32 + ((cfrag ^ swzr) << 3)];
        }

        __syncthreads();   // fragment reads complete -> Bs overwrite safe
        if (k0 + 32 < K) {
            gload16(pb0 + k0 + 32, lB0);   // async; drains at next top barrier
            gload16(pb1 + k0 + 32, lB1);
        }

        #pragma unroll
        for (int mt = 0; mt < 4; ++mt)
            #pragma unroll
            for (int nt = 0; nt < 4; ++nt)
                acc[mt][nt] = __builtin_amdgcn_mfma_f32_16x16x32_bf16(
                    af[mt], bfv[nt], acc[mt][nt], 0, 0, 0);
    }

    // ---- epilogue: bias + relu -> bf16 hA (global), old gemm1 value order ----
    #pragma unroll
    for (int mt = 0; mt < 4; ++mt) {
        #pragma unroll
        for (int nt = 0; nt < 4; ++nt) {
            #pragma unroll
            for (int r = 0; r < 4; ++r) {
                int grow = m0 + wm + mt * 16 + (lane >> 4) * 4 + r;
                int gcol = wn + nt * 16 + fr;
                if (grow < M) {
                    float v = acc[mt][nt][r] + b1[gcol];
                    hA[(size_t)grow * 256 + gcol] = f2bf(fmaxf(v, 0.f));
                }
            }
        }
    }
}

// ---------------- fused layer 2: gather + GEMM + classifier ----------------
// R16 structure; hT swizzle upgraded from window-slot (1.5M bank-conflict
// cycles) to FULL chunk-XOR  chunk' = chunk ^ (row&7)  (R12-verified layout,
// 500K conflicts). Same values/k-order -> bitwise-identical output.

__global__ __launch_bounds__(512, 4) void layer2_fused_kernel(
    const short* __restrict__ hA,     // [M,256] bf16 (layer-1 output)
    const int* __restrict__ deg, const int* __restrict__ eslot,
    const short* __restrict__ Wt2,    // [256 cols][256 k] bf16
    const float* __restrict__ b2,
    const short* __restrict__ Wtc,    // [32 cols][256 k] bf16
    const float* __restrict__ bc,
    float* __restrict__ out,          // [M,32] fp32
    int M)
{
    const int K = 256;
    __shared__ short smem[128 * 256 + 256 * 32];   // hT/T 64KB + Bs 16KB = 80KB
    short* hT = smem;
    short* Bs = smem + 128 * 256;

    const int tid = threadIdx.x;
    const int wave = tid >> 6, lane = tid & 63;
    const int m0 = blockIdx.x * 128;

    // ---- B staging geometry (Wt2 rows 0..255, 32 shorts per K-step) ----
    const int srow = tid >> 2;               // 0..127
    const int cdst = tid & 3;
    const int lrB0 = srow, lrB1 = 128 + srow;
    const int cg0 = cdst ^ ((lrB0 >> 1) & 3);
    const int cg1 = cdst ^ ((lrB1 >> 1) & 3);
    const short* pb0 = Wt2 + (size_t)lrB0 * K + cg0 * 8;
    const short* pb1 = Wt2 + (size_t)lrB1 * K + cg1 * 8;
    short* lB0 = &Bs[(wave * 16) * 32];
    short* lB1 = &Bs[(128 + wave * 16) * 32];

    // pre-issue K-step 0 staging (no deps; lands during the gather phase)
    gload16(pb0, lB0);
    gload16(pb1, lB1);

    // ---- Phase 1 (peeled): gather 128 rows of hB into hT (F=256) ----
    {
        const int grp = tid >> 5;            // 0..15: node group
        const int gl  = tid & 31;            // feature chunk 0..31
        const int f   = gl * 8;
        for (int r0 = 0; r0 < 128; r0 += 16) {
            int r = r0 + grp;
            int node = m0 + r; if (node >= M) node = M - 1;
            const int* bucket = eslot + (size_t)node * CAP;
            int4 sa = *(const int4*)(bucket + 0);
            int4 sb = *(const int4*)(bucket + 4);
            int4 sc = *(const int4*)(bucket + 8);
            int4 sd = *(const int4*)(bucket + 12);
            int dg = deg[node];
            short8 hv = *(const short8*)(hA + (size_t)node * 256 + f);
            if (dg > CAP) dg = CAP;
            float di = rsqrtf((float)dg + 1.0f);
            float w = di * di;
            float a[8];
            #pragma unroll
            for (int j = 0; j < 8; ++j) a[j] = bf2f(hv[j]) * w;

            // round 0: slots 0..7 unconditional (guards -> index 0 / weight 0)
            int id[8];
            id[0] = (0 < dg) ? sa.x : 0;
            id[1] = (1 < dg) ? sa.y : 0;
            id[2] = (2 < dg) ? sa.z : 0;
            id[3] = (3 < dg) ? sa.w : 0;
            id[4] = (4 < dg) ? sb.x : 0;
            id[5] = (5 < dg) ? sb.y : 0;
            id[6] = (6 < dg) ? sb.z : 0;
            id[7] = (7 < dg) ? sb.w : 0;
            short8 v[8];
            int dd[8];
            #pragma unroll
            for (int t = 0; t < 8; ++t) {
                v[t] = *(const short8*)(hA + (size_t)id[t] * 256 + f);
                dd[t] = deg[id[t]];
            }
            float wg[8];
            #pragma unroll
            for (int t = 0; t < 8; ++t)
                wg[t] = (t < dg) ? rsqrtf((float)dd[t] + 1.0f) * di : 0.f;
            #pragma unroll
            for (int t = 0; t < 8; ++t)
                #pragma unroll
                for (int j = 0; j < 8; ++j)
                    a[j] = fmaf(bf2f(v[t][j]), wg[t], a[j]);

            // round 1: slots 8..15 (~16% of rows)
            if (dg > 8) {
                int id1[8];
                id1[0] = sc.x;
                id1[1] = (9  < dg) ? sc.y : 0;
                id1[2] = (10 < dg) ? sc.z : 0;
                id1[3] = (11 < dg) ? sc.w : 0;
                id1[4] = (12 < dg) ? sd.x : 0;
                id1[5] = (13 < dg) ? sd.y : 0;
                id1[6] = (14 < dg) ? sd.z : 0;
                id1[7] = (15 < dg) ? sd.w : 0;
                short8 v1[8];
                int dd1[8];
                #pragma unroll
                for (int t = 0; t < 8; ++t) {
                    v1[t] = *(const short8*)(hA + (size_t)id1[t] * 256 + f);
                    dd1[t] = deg[id1[t]];
                }
                float wg1[8];
                #pragma unroll
                for (int t = 0; t < 8; ++t)
                    wg1[t] = (8 + t < dg) ? rsqrtf((float)dd1[t] + 1.0f) * di : 0.f;
                #pragma unroll
                for (int t = 0; t < 8; ++t)
                    #pragma unroll
                    for (int j = 0; j < 8; ++j)
                        a[j] = fmaf(bf2f(v1[t][j]), wg1[t], a[j]);

                // rare tail: deg > 16 (P ~ 2.5e-4), original 4-wide loop
                for (int e = 16; e < dg; e += 4) {
                    int4 s4 = *(const int4*)(bucket + e);
                    int i0 = s4.x;
                    int i1 = (e + 1 < dg) ? s4.y : 0;
                    int i2 = (e + 2 < dg) ? s4.z : 0;
                    int i3 = (e + 3 < dg) ? s4.w : 0;
                    int d0 = deg[i0], d1 = deg[i1], d2 = deg[i2], d3 = deg[i3];
                    short8 u0 = *(const short8*)(hA + (size_t)i0 * 256 + f);
                    short8 u1 = *(const short8*)(hA + (size_t)i1 * 256 + f);
                    short8 u2 = *(const short8*)(hA + (size_t)i2 * 256 + f);
                    short8 u3 = *(const short8*)(hA + (size_t)i3 * 256 + f);
                    float w0 = rsqrtf((float)d0 + 1.0f) * di;
                    float w1 = (e + 1 < dg) ? rsqrtf((float)d1 + 1.0f) * di : 0.f;
                    float w2 = (e + 2 < dg) ? rsqrtf((float)d2 + 1.0f) * di : 0.f;
                    float w3 = (e + 3 < dg) ? rsqrtf((float)d3 + 1.0f) * di : 0.f;
                    #pragma unroll
                    for (int j = 0; j < 8; ++j) {
                        a[j] = fmaf(bf2f(u0[j]), w0, a[j]);
                        a[j] = fmaf(bf2f(u1[j]), w1, a[j]);
                        a[j] = fmaf(bf2f(u2[j]), w2, a[j]);
                        a[j] = fmaf(bf2f(u3[j]), w3, a[j]);
                    }
                }
            }
            short8 o;
            #pragma unroll
            for (int j = 0; j < 8; ++j) o[j] = f2bf(a[j]);
            *(short8*)&hT[r * 256 + ((gl ^ (r & 7)) << 3)] = o;   // full chunk-XOR
        }
    }

    // ---- Phase 2: T = relu(hT @ W2 + b2), staging overlapped with MFMA ----
    const int wm = (wave >> 2) * 64;         // 0,64
    const int wn = (wave & 3) * 64;          // 0,64,128,192
    const int fr = lane & 15;
    const int cfrag = lane >> 4;
    const int rk = fr & 7;                   // hT swizzle key (wave rows +16k)
    const int swzr = (fr >> 1) & 3;          // Bs swizzle key

    f32x4 acc[4][4] = {};
    for (int k0 = 0; k0 < K; k0 += 32) {
        __syncthreads();   // Bs[k0] resident; hT writes visible (iter 0); prior reads done

        const int cswz = (((k0 >> 3) + cfrag) ^ rk) << 3;   // hT swizzled chunk offset
        short8 af[4], bfv[4];
        #pragma unroll
        for (int mt = 0; mt < 4; ++mt)
            af[mt] = *(const short8*)&hT[(wm + mt * 16 + fr) * 256 + cswz];
        #pragma unroll
        for (int nt = 0; nt < 4; ++nt) {
            int rr = wn + nt * 16 + fr;
            bfv[nt] = *(const short8*)&Bs[rr * 32 + ((cfrag ^ swzr) << 3)];
        }

        __syncthreads();   // fragment reads complete -> Bs overwrite safe
        if (k0 + 32 < K) {
            gload16(pb0 + k0 + 32, lB0);   // async; drains at next top barrier
            gload16(pb1 + k0 + 32, lB1);
        }

        #pragma unroll
        for (int mt = 0; mt < 4; ++mt)
            #pragma unroll
            for (int nt = 0; nt < 4; ++nt)
                acc[mt][nt] = __builtin_amdgcn_mfma_f32_16x16x32_bf16(
                    af[mt], bfv[nt], acc[mt][nt], 0, 0, 0);
    }

    // ---- Phase 3: bias+relu -> bf16 T tile (aliases hT; same full XOR) ----
    #pragma unroll
    for (int mt = 0; mt < 4; ++mt) {
        #pragma unroll
        for (int nt = 0; nt < 4; ++nt) {
            #pragma unroll
            for (int r = 0; r < 4; ++r) {
                int lrow = wm + mt * 16 + (lane >> 4) * 4 + r;
                int gcol = wn + nt * 16 + fr;
                float v = acc[mt][nt][r] + b2[gcol];
                int cs = (gcol >> 3) ^ (lrow & 7);
                hT[lrow * 256 + cs * 8 + (gcol & 7)] = f2bf(fmaxf(v, 0.f));
            }
        }
    }
    __syncthreads();

    // ---- Phase 4: out = T @ Wc + bc (gemmc's exact k-order / C mapping) ----
    f32x4 c2[2] = {};
    for (int k0 = 0; k0 < K; k0 += 32) {
        const int cswz = (((k0 >> 3) + cfrag) ^ rk) << 3;   // row&7 == fr&7 here too
        short8 a8 = *(const short8*)&hT[(wave * 16 + fr) * 256 + cswz];
        #pragma unroll
        for (int nt = 0; nt < 2; ++nt) {
            short8 b8 = *(const short8*)(Wtc + (size_t)(nt * 16 + fr) * K +
                                         (cfrag << 3) + k0);
            c2[nt] = __builtin_amdgcn_mfma_f32_16x16x32_bf16(a8, b8, c2[nt], 0, 0, 0);
        }
    }
    #pragma unroll
    for (int nt = 0; nt < 2; ++nt) {
        #pragma unroll
        for (int r = 0; r < 4; ++r) {
            int grow = m0 + wave * 16 + (lane >> 4) * 4 + r;
            int gcol = nt * 16 + fr;
            if (grow < M)
                out[(size_t)grow * 32 + gcol] = c2[nt][r] + bc[gcol];
        }
    }
}

// ---------------- launch ----------------

extern "C" void kernel_launch(void* const* d_in, const int* in_sizes, int n_in,
                              void* d_out, int out_size, void* d_ws, size_t ws_size,
                              hipStream_t stream) {
    const float* x  = (const float*)d_in[0];
    const int*   ei = (const int*)d_in[1];
    const float* W1 = (const float*)d_in[2];
    const float* b1 = (const float*)d_in[3];
    const float* W2 = (const float*)d_in[4];
    const float* b2 = (const float*)d_in[5];
    const float* Wc = (const float*)d_in[6];
    const float* bc = (const float*)d_in[7];
    float* out = (float*)d_out;

    const int E = in_sizes[1] / 2;
    const int N = in_sizes[0] / 128;
    const int* src = ei;
    const int* dst = ei + E;

    // workspace layout (shorts first, 16B aligned)
    short* xb   = (short*)d_ws;                     // N*128
    short* hA   = xb + (size_t)N * 128;             // N*256
    short* Wt1  = hA + (size_t)N * 256;             // 256*128
    short* Wt2  = Wt1 + 256 * 128;                  // 256*256
    short* Wtc  = Wt2 + 256 * 256;                  // 32*256
    int*   deg  = (int*)(Wtc + 32 * 256);           // N
    int*   eslot= deg + N;                          // N*CAP (16B-aligned: N*CAP*4)

    const int TB = 256;

    hipMemsetAsync(deg, 0, (size_t)N * sizeof(int), stream);

    const int prep_total = N * 16 + 128 * 256 + 256 * 256 + 256 * 32 + E;
    prep_kernel<<<(prep_total + TB - 1) / TB, TB, 0, stream>>>(
        x, W1, W2, Wc, src, dst, xb, Wt1, Wt2, Wtc, deg, eslot, N, E);

    const int gy = (N + 127) / 128;

    // layer 1, fully fused: hA = relu((A_hat @ X) @ W1 + b1)
    layer1_fused_kernel<<<gy, 512, 0, stream>>>(
        xb, deg, eslot, Wt1, b1, hA, N);

    // layer 2 + classifier, fully fused:
    //   out = relu((A_hat @ hA) @ W2 + b2) @ Wc + bc
    layer2_fused_kernel<<<gy, 512, 0, stream>>>(
        hA, deg, eslot, Wt2, b2, Wtc, bc, out, N);
}